// Round 3
// baseline (141.150 us; speedup 1.0000x reference)
//
#include <hip/hip_runtime.h>

#define H 1024
#define BSZ 64
#define TT 512
#define BT (BSZ * TT)   // 32768 rows
#define NSPLIT 4        // N=1024 / BN=256
#define NTILES 16       // K tiles = H / 64

using bf16x8 = __attribute__((ext_vector_type(8))) __bf16;
using f32x4  = __attribute__((ext_vector_type(4))) float;

__device__ __forceinline__ unsigned short f2bf(float f) {
  unsigned u = __float_as_uint(f);
  u += 0x7FFF + ((u >> 16) & 1);   // RTN-even
  return (unsigned short)(u >> 16);
}
__device__ __forceinline__ float bf2f(unsigned short h) {
  return __uint_as_float(((unsigned)h) << 16);
}

#define GLDS(gp, lp) \
  __builtin_amdgcn_global_load_lds( \
      (const __attribute__((address_space(1))) void*)(gp), \
      (__attribute__((address_space(3))) void*)(lp), 16, 0, 0)

// ---------------- Kernel 1: LayerNorm + bf16 cast ----------------
__global__ __launch_bounds__(256) void ln_kernel(
    const float* __restrict__ in, const float* __restrict__ gamma,
    const float* __restrict__ beta, unsigned short* __restrict__ xb) {
  const int row = blockIdx.x;
  const int tid = threadIdx.x;
  const float4 xv = reinterpret_cast<const float4*>(in + (size_t)row * H)[tid];
  float s  = xv.x + xv.y + xv.z + xv.w;
  float ss = xv.x * xv.x + xv.y * xv.y + xv.z * xv.z + xv.w * xv.w;
#pragma unroll
  for (int off = 32; off >= 1; off >>= 1) {
    s  += __shfl_xor(s, off);
    ss += __shfl_xor(ss, off);
  }
  __shared__ float red[2][4];
  const int w = tid >> 6;
  if ((tid & 63) == 0) { red[0][w] = s; red[1][w] = ss; }
  __syncthreads();
  const float tot  = red[0][0] + red[0][1] + red[0][2] + red[0][3];
  const float tot2 = red[1][0] + red[1][1] + red[1][2] + red[1][3];
  const float mu   = tot * (1.0f / H);
  const float var  = tot2 * (1.0f / H) - mu * mu;
  const float rstd = rsqrtf(var + 1e-5f);
  const float4 g  = reinterpret_cast<const float4*>(gamma)[tid];
  const float4 bt = reinterpret_cast<const float4*>(beta)[tid];
  ushort4 o;
  o.x = f2bf((xv.x - mu) * rstd * g.x + bt.x);
  o.y = f2bf((xv.y - mu) * rstd * g.y + bt.y);
  o.z = f2bf((xv.z - mu) * rstd * g.z + bt.z);
  o.w = f2bf((xv.w - mu) * rstd * g.w + bt.w);
  reinterpret_cast<ushort4*>(xb + (size_t)row * H)[tid] = o;
}

// ---------------- Kernel 2: W -> bf16 ----------------
__global__ __launch_bounds__(256) void wcvt_kernel(
    const float* __restrict__ Win, unsigned short* __restrict__ wb) {
  const size_t i = (size_t)blockIdx.x * 1024 + (size_t)threadIdx.x * 4;
  const float4 xv = *reinterpret_cast<const float4*>(Win + i);
  ushort4 o;
  o.x = f2bf(xv.x); o.y = f2bf(xv.y); o.z = f2bf(xv.z); o.w = f2bf(xv.w);
  *reinterpret_cast<ushort4*>(wb + i) = o;
}

// ---------------- Kernel 3: fused scores GEMM (256x256, 8-phase) --------
// spart[nt][m] = sum_{d in [nt*256,nt*256+256)} tanh(Wout[m,d]+bW[d])*v[d]
//
// 8-phase schedule (m201 template adapted): iteration = 2 K-tiles
// (tile t2 -> buf0, t2+1 -> buf1; fixed LDS regions by parity).
// Phase = {8|4 ds_read_b128, 1 half-unit stage (2 gloads), barrier,
//          lgkmcnt(0), 16 MFMA (setprio), [vmcnt @P4/P8], barrier}.
// Stage-unit ledger (1 unit = 2 gloads/thread):
//   P1: A-b1kh1<-t2+1  P2: B-b1kh1<-t2+1  P3: A-b0kh0<-t2+2  P4: B-b0kh0
//   P5: A-b0kh1<-t2+2  P6: B-b0kh1        P7: A-b1kh0<-t2+3  P8: B-b1kh0
// vmcnt(4) @P4 covers {prev-P7,prev-P8,P1,P2}; vmcnt(4) @P8 covers {P3..P6};
// 2 units always in flight; final iter drains with vmcnt(0) @P4.
__global__ __launch_bounds__(512, 2) void score_gemm(
    const unsigned short* __restrict__ xb, const unsigned short* __restrict__ wb,
    const float* __restrict__ bW, const float* __restrict__ v,
    float* __restrict__ spart) {
  // [2 buf][2 khalf][256 rows][32 k] bf16 per matrix = 64 KiB each
  __shared__ unsigned short As[32768];
  __shared__ unsigned short Bs[32768];
  __shared__ float s_red[4][256];

  const int tid  = threadIdx.x;
  const int w    = tid >> 6, lane = tid & 63;
  const int wm   = w >> 2, wn = w & 3;      // 2 M-waves x 4 N-waves

  // bijective XCD swizzle (512 blocks % 8 == 0)
  const int bid0 = blockIdx.x;
  const int bid  = (bid0 & 7) * 64 + (bid0 >> 3);
  const int mt = bid & 127, nt = bid >> 7;
  const int mbase = mt * 256, nbase = nt * 256;

  // --- staging geometry: one unit = 256 rows x 32 k of one matrix ---
  const int srow = lane >> 2;                                  // row in chunk
  const int swz8 = ((lane & 3) ^ ((lane >> 3) & 3)) * 8;       // pre-swizzled src col
  const int ch0 = w, ch1 = 8 + w;                              // this wave's chunks

  const unsigned short* gA = xb + (size_t)mbase * H;
  const unsigned short* gB = wb + (size_t)nbase * H;

  auto stage_unit = [&](const unsigned short* gbase, unsigned short* lbase,
                        int tk, int kh, int buf) {
    const int ro   = (buf * 2 + kh) * 8192;
    const int gcol = tk * 64 + kh * 32 + swz8;
    GLDS(gbase + (size_t)(ch0 * 16 + srow) * H + gcol, &lbase[ro + ch0 * 512]);
    GLDS(gbase + (size_t)(ch1 * 16 + srow) * H + gcol, &lbase[ro + ch1 * 512]);
  };

  // --- fragment-read geometry (swizzle-matched) ---
  const int acoff = (((lane >> 4) ^ (((lane & 15) >> 1) & 3)) * 8);
  const int arow0 = wm * 128 + (lane & 15);
  const int brow0 = wn * 64  + (lane & 15);

  f32x4 acc[8][4];
#pragma unroll
  for (int mi = 0; mi < 8; mi++)
#pragma unroll
    for (int ni = 0; ni < 4; ni++) acc[mi][ni] = (f32x4){0.f, 0.f, 0.f, 0.f};

#define LDA4(DST, RO, F0) \
  _Pragma("unroll") \
  for (int f = 0; f < 4; f++) \
    DST[f] = *reinterpret_cast<const bf16x8*>(&As[(RO) + (arow0 + ((F0) + f) * 16) * 32 + acoff]);
#define LDB4(DST, RO) \
  _Pragma("unroll") \
  for (int f = 0; f < 4; f++) \
    DST[f] = *reinterpret_cast<const bf16x8*>(&Bs[(RO) + (brow0 + f * 16) * 32 + acoff]);
#define BARMID() \
  __builtin_amdgcn_s_barrier(); \
  asm volatile("s_waitcnt lgkmcnt(0)" ::: "memory"); \
  __builtin_amdgcn_sched_barrier(0);
#define BAREND() __builtin_amdgcn_s_barrier();
#define MMAQ(M0, AF, BF) \
  __builtin_amdgcn_s_setprio(1); \
  _Pragma("unroll") \
  for (int mi = 0; mi < 4; mi++) \
    _Pragma("unroll") \
    for (int ni = 0; ni < 4; ni++) \
      acc[(M0) + mi][ni] = __builtin_amdgcn_mfma_f32_16x16x32_bf16(AF[mi], BF[ni], acc[(M0) + mi][ni], 0, 0, 0); \
  __builtin_amdgcn_s_setprio(0);

  // prologue: tile0 (buf0) + tile1 kh0 (buf1) = 6 units, keep last 2 in flight
  stage_unit(gA, As, 0, 0, 0);
  stage_unit(gB, Bs, 0, 0, 0);
  stage_unit(gA, As, 0, 1, 0);
  stage_unit(gB, Bs, 0, 1, 0);
  stage_unit(gA, As, 1, 0, 1);
  stage_unit(gB, Bs, 1, 0, 1);
  asm volatile("s_waitcnt vmcnt(4)" ::: "memory");
  __builtin_amdgcn_s_barrier();

  for (int it = 0; it < NTILES / 2; ++it) {
    const int t2 = it * 2;
    const bool pf = (t2 + 2 < NTILES);
    bf16x8 a0[4], a1[4], b0[4];
    // ---- P1: buf0 kh0, quadrant M0-3 ----
    LDA4(a0, 0, 0) LDB4(b0, 0)
    stage_unit(gA, As, t2 + 1, 1, 1);
    BARMID() MMAQ(0, a0, b0) BAREND()
    // ---- P2: buf0 kh0, quadrant M4-7 ----
    LDA4(a1, 0, 4)
    stage_unit(gB, Bs, t2 + 1, 1, 1);
    BARMID() MMAQ(4, a1, b0) BAREND()
    // ---- P3: buf0 kh1, M0-3 ----
    LDA4(a0, 8192, 0) LDB4(b0, 8192)
    if (pf) stage_unit(gA, As, t2 + 2, 0, 0);
    BARMID() MMAQ(0, a0, b0) BAREND()
    // ---- P4: buf0 kh1, M4-7 ----
    LDA4(a1, 8192, 4)
    if (pf) stage_unit(gB, Bs, t2 + 2, 0, 0);
    BARMID() MMAQ(4, a1, b0)
    if (pf) { asm volatile("s_waitcnt vmcnt(4)" ::: "memory"); }
    else    { asm volatile("s_waitcnt vmcnt(0)" ::: "memory"); }
    BAREND()
    // ---- P5: buf1 kh0, M0-3 ----
    LDA4(a0, 16384, 0) LDB4(b0, 16384)
    if (pf) stage_unit(gA, As, t2 + 2, 1, 0);
    BARMID() MMAQ(0, a0, b0) BAREND()
    // ---- P6: buf1 kh0, M4-7 ----
    LDA4(a1, 16384, 4)
    if (pf) stage_unit(gB, Bs, t2 + 2, 1, 0);
    BARMID() MMAQ(4, a1, b0) BAREND()
    // ---- P7: buf1 kh1, M0-3 ----
    LDA4(a0, 24576, 0) LDB4(b0, 24576)
    if (pf) stage_unit(gA, As, t2 + 3, 0, 1);
    BARMID() MMAQ(0, a0, b0) BAREND()
    // ---- P8: buf1 kh1, M4-7 ----
    LDA4(a1, 24576, 4)
    if (pf) stage_unit(gB, Bs, t2 + 3, 0, 1);
    BARMID() MMAQ(4, a1, b0)
    if (pf) { asm volatile("s_waitcnt vmcnt(4)" ::: "memory"); }
    BAREND()
  }

  // ---- epilogue: tanh(.+bW)*v, reduce over N within block ----
  float sp[8][4];
#pragma unroll
  for (int mi = 0; mi < 8; mi++)
#pragma unroll
    for (int r = 0; r < 4; r++) sp[mi][r] = 0.f;

#pragma unroll
  for (int ni = 0; ni < 4; ni++) {
    const int col = nbase + wn * 64 + ni * 16 + (lane & 15);
    const float bwv = bW[col];
    const float vv  = v[col];
#pragma unroll
    for (int mi = 0; mi < 8; mi++)
#pragma unroll
      for (int r = 0; r < 4; r++) {
        float xv = acc[mi][ni][r] + bwv;
        xv = fminf(fmaxf(xv, -15.f), 15.f);
        const float e = __expf(2.f * xv);
        sp[mi][r] += vv * (e - 1.f) / (e + 1.f);   // tanh
      }
  }
#pragma unroll
  for (int mi = 0; mi < 8; mi++)
#pragma unroll
    for (int r = 0; r < 4; r++) {
      float sv = sp[mi][r];
      sv += __shfl_xor(sv, 1);
      sv += __shfl_xor(sv, 2);
      sv += __shfl_xor(sv, 4);
      sv += __shfl_xor(sv, 8);
      sp[mi][r] = sv;
    }
  if ((lane & 15) == 0) {
#pragma unroll
    for (int mi = 0; mi < 8; mi++)
#pragma unroll
      for (int r = 0; r < 4; r++)
        s_red[wn][wm * 128 + mi * 16 + (lane >> 4) * 4 + r] = sp[mi][r];
  }
  __syncthreads();
  if (tid < 256)
    spart[(size_t)nt * BT + mbase + tid] =
        s_red[0][tid] + s_red[1][tid] + s_red[2][tid] + s_red[3][tid];
}

// ---------------- Kernel 4: softmax over T per batch ----------------
__global__ __launch_bounds__(512) void softmax_kernel(
    const float* __restrict__ spart, const float* __restrict__ bv,
    float* __restrict__ wout) {
  const int b = blockIdx.x, t = threadIdx.x;
  float s = bv[0];
#pragma unroll
  for (int p = 0; p < NSPLIT; p++) s += spart[(size_t)p * BT + b * TT + t];
  if (s != s) s = 0.f;                       // nan_to_num
  s = fminf(fmaxf(s, -10.f), 10.f);          // clip
  float m = s;
#pragma unroll
  for (int off = 32; off >= 1; off >>= 1) m = fmaxf(m, __shfl_xor(m, off));
  __shared__ float redm[8], reds[8];
  const int w = t >> 6;
  if ((t & 63) == 0) redm[w] = m;
  __syncthreads();
  m = redm[0];
#pragma unroll
  for (int i = 1; i < 8; i++) m = fmaxf(m, redm[i]);
  const float e = expf(s - m);
  float su = e;
#pragma unroll
  for (int off = 32; off >= 1; off >>= 1) su += __shfl_xor(su, off);
  if ((t & 63) == 0) reds[w] = su;
  __syncthreads();
  su = 0.f;
#pragma unroll
  for (int i = 0; i < 8; i++) su += reds[i];
  wout[b * TT + t] = e / su;
}

// ---------------- Kernel 5: context partials over t-chunks ----------------
__global__ __launch_bounds__(256) void ctx_part_kernel(
    const unsigned short* __restrict__ xb, const float* __restrict__ wts,
    float* __restrict__ ctxp) {
  const int b = blockIdx.x, c = blockIdx.y, tid = threadIdx.x;
  const int h = tid * 4;
  float a0 = 0.f, a1 = 0.f, a2 = 0.f, a3 = 0.f;
  const unsigned short* xrow = xb + ((size_t)(b * TT + c * 64)) * H + h;
  const float* wrow = wts + b * TT + c * 64;
  for (int t = 0; t < 64; t++) {
    const float wgt = wrow[t];
    const ushort4 xv = *reinterpret_cast<const ushort4*>(xrow + (size_t)t * H);
    a0 += wgt * bf2f(xv.x);
    a1 += wgt * bf2f(xv.y);
    a2 += wgt * bf2f(xv.z);
    a3 += wgt * bf2f(xv.w);
  }
  float4 o = {a0, a1, a2, a3};
  *reinterpret_cast<float4*>(ctxp + ((size_t)c * BSZ + b) * H + h) = o;
}

// ---------------- Kernel 6: context reduce ----------------
__global__ __launch_bounds__(256) void ctx_reduce_kernel(
    const float* __restrict__ ctxp, float* __restrict__ out) {
  const int idx = blockIdx.x * 256 + threadIdx.x;  // 0..65535 = b*H+h
  float s = 0.f;
#pragma unroll
  for (int c = 0; c < 8; c++) s += ctxp[(size_t)c * (BSZ * H) + idx];
  out[idx] = s;
}

extern "C" void kernel_launch(void* const* d_in, const int* in_sizes, int n_in,
                              void* d_out, int out_size, void* d_ws, size_t ws_size,
                              hipStream_t stream) {
  const float* lstm  = (const float*)d_in[0];
  const float* W     = (const float*)d_in[1];
  const float* bW    = (const float*)d_in[2];
  const float* v     = (const float*)d_in[3];
  const float* bv    = (const float*)d_in[4];
  const float* gamma = (const float*)d_in[5];
  const float* beta  = (const float*)d_in[6];
  float* out = (float*)d_out;

  char* ws = (char*)d_ws;
  unsigned short* xb = (unsigned short*)ws;                                   // 64 MiB
  unsigned short* wb = (unsigned short*)(ws + (size_t)BT * H * 2);            // 2 MiB
  float* spart = (float*)(ws + (size_t)BT * H * 2 + (size_t)H * H * 2);       // 512 KiB
  float* ctxp  = (float*)((char*)spart + (size_t)NSPLIT * BT * 4);            // 2 MiB

  float* weights_out = out + BSZ * H;   // context first (65536), then weights (32768)

  ln_kernel<<<BT, 256, 0, stream>>>(lstm, gamma, beta, xb);
  wcvt_kernel<<<(H * H) / 1024, 256, 0, stream>>>(W, wb);
  score_gemm<<<512, 512, 0, stream>>>(xb, wb, bW, v, spart);
  softmax_kernel<<<BSZ, TT, 0, stream>>>(spart, bv, weights_out);
  ctx_part_kernel<<<dim3(BSZ, 8), 256, 0, stream>>>(xb, weights_out, ctxp);
  ctx_reduce_kernel<<<(BSZ * H) / 256, 256, 0, stream>>>(ctxp, out);
}

// Round 4
// 140.151 us; speedup vs baseline: 1.0071x; 1.0071x over previous
//
#include <hip/hip_runtime.h>

#define H 1024
#define BSZ 64
#define TT 512
#define BT (BSZ * TT)   // 32768 rows
#define NSPLIT 4        // N=1024 / BN=256
#define NTILES 16       // K tiles = H / 64

using bf16x8 = __attribute__((ext_vector_type(8))) __bf16;
using f32x4  = __attribute__((ext_vector_type(4))) float;

__device__ __forceinline__ unsigned short f2bf(float f) {
  unsigned u = __float_as_uint(f);
  u += 0x7FFF + ((u >> 16) & 1);   // RTN-even
  return (unsigned short)(u >> 16);
}
__device__ __forceinline__ float bf2f(unsigned short h) {
  return __uint_as_float(((unsigned)h) << 16);
}

#define GLDS(gp, lp) \
  __builtin_amdgcn_global_load_lds( \
      (const __attribute__((address_space(1))) void*)(gp), \
      (__attribute__((address_space(3))) void*)(lp), 16, 0, 0)

// ---------------- Kernel 1: LayerNorm + bf16 cast ----------------
__global__ __launch_bounds__(256) void ln_kernel(
    const float* __restrict__ in, const float* __restrict__ gamma,
    const float* __restrict__ beta, unsigned short* __restrict__ xb) {
  const int row = blockIdx.x;
  const int tid = threadIdx.x;
  const float4 xv = reinterpret_cast<const float4*>(in + (size_t)row * H)[tid];
  float s  = xv.x + xv.y + xv.z + xv.w;
  float ss = xv.x * xv.x + xv.y * xv.y + xv.z * xv.z + xv.w * xv.w;
#pragma unroll
  for (int off = 32; off >= 1; off >>= 1) {
    s  += __shfl_xor(s, off);
    ss += __shfl_xor(ss, off);
  }
  __shared__ float red[2][4];
  const int w = tid >> 6;
  if ((tid & 63) == 0) { red[0][w] = s; red[1][w] = ss; }
  __syncthreads();
  const float tot  = red[0][0] + red[0][1] + red[0][2] + red[0][3];
  const float tot2 = red[1][0] + red[1][1] + red[1][2] + red[1][3];
  const float mu   = tot * (1.0f / H);
  const float var  = tot2 * (1.0f / H) - mu * mu;
  const float rstd = rsqrtf(var + 1e-5f);
  const float4 g  = reinterpret_cast<const float4*>(gamma)[tid];
  const float4 bt = reinterpret_cast<const float4*>(beta)[tid];
  ushort4 o;
  o.x = f2bf((xv.x - mu) * rstd * g.x + bt.x);
  o.y = f2bf((xv.y - mu) * rstd * g.y + bt.y);
  o.z = f2bf((xv.z - mu) * rstd * g.z + bt.z);
  o.w = f2bf((xv.w - mu) * rstd * g.w + bt.w);
  reinterpret_cast<ushort4*>(xb + (size_t)row * H)[tid] = o;
}

// ---------------- Kernel 2: W -> bf16 ----------------
__global__ __launch_bounds__(256) void wcvt_kernel(
    const float* __restrict__ Win, unsigned short* __restrict__ wb) {
  const size_t i = (size_t)blockIdx.x * 1024 + (size_t)threadIdx.x * 4;
  const float4 xv = *reinterpret_cast<const float4*>(Win + i);
  ushort4 o;
  o.x = f2bf(xv.x); o.y = f2bf(xv.y); o.z = f2bf(xv.z); o.w = f2bf(xv.w);
  *reinterpret_cast<ushort4*>(wb + i) = o;
}

// ---------------- Kernel 3: fused scores GEMM (256x256, pipelined 8-phase)
// spart[nt][m] = sum_{d in [nt*256,nt*256+256)} tanh(Wout[m,d]+bW[d])*v[d]
//
// Phase = {barrier+fence; stage 1 unit (2 GLDS); ds_reads for NEXT MFMA;
//          setprio(1) MFMA setprio(0)}. No manual lgkmcnt / sched_barrier:
// compiler emits partial lgkmcnt(N) so read latency hides under MFMA.
// Stage-unit roles per iter (1 unit = 2 gloads/thread):
//   P1: A-b1kh1<-t2+1  P2: B-b1kh1  P3: A-b0kh0<-t2+2  P4: B-b0kh0
//   P5: A-b0kh1<-t2+2  P6: B-b0kh1  P7: A-b1kh0<-t2+3  P8: B-b1kh0
// vmcnt(4) at end of P4 covers {prev-P7,prev-P8,P1,P2}; at end of P8 covers
// {P3..P6}; 2 units stay in flight. Reads for phase p are consumed by an
// MFMA issued before barrier p+1, so a stage into region R at phase p+2 is
// ordered after all reads of R (barrier transitivity).
__global__ __launch_bounds__(512, 2) void score_gemm(
    const unsigned short* __restrict__ xb, const unsigned short* __restrict__ wb,
    const float* __restrict__ bW, const float* __restrict__ v,
    float* __restrict__ spart) {
  // [2 buf][2 khalf][256 rows][32 k] bf16 per matrix = 64 KiB each
  __shared__ unsigned short As[32768];
  __shared__ unsigned short Bs[32768];
  __shared__ float s_red[4][256];

  const int tid  = threadIdx.x;
  const int w    = tid >> 6, lane = tid & 63;
  const int wm   = w >> 2, wn = w & 3;      // 2 M-waves x 4 N-waves

  // bijective XCD swizzle (512 blocks % 8 == 0)
  const int bid0 = blockIdx.x;
  const int bid  = (bid0 & 7) * 64 + (bid0 >> 3);
  const int mt = bid & 127, nt = bid >> 7;
  const int mbase = mt * 256, nbase = nt * 256;

  // --- staging geometry: one unit = 256 rows x 32 k of one matrix ---
  const int srow = lane >> 2;                                  // row in chunk
  const int swz8 = ((lane & 3) ^ ((lane >> 3) & 3)) * 8;       // pre-swizzled src col
  const int ch0 = w, ch1 = 8 + w;                              // this wave's chunks

  const unsigned short* gA = xb + (size_t)mbase * H;
  const unsigned short* gB = wb + (size_t)nbase * H;

  auto stage_unit = [&](const unsigned short* gbase, unsigned short* lbase,
                        int tk, int kh, int buf) {
    const int ro   = (buf * 2 + kh) * 8192;
    const int gcol = tk * 64 + kh * 32 + swz8;
    GLDS(gbase + (size_t)(ch0 * 16 + srow) * H + gcol, &lbase[ro + ch0 * 512]);
    GLDS(gbase + (size_t)(ch1 * 16 + srow) * H + gcol, &lbase[ro + ch1 * 512]);
  };

  // --- fragment-read geometry (swizzle-matched) ---
  const int acoff = (((lane >> 4) ^ (((lane & 15) >> 1) & 3)) * 8);
  const int arow0 = wm * 128 + (lane & 15);
  const int brow0 = wn * 64  + (lane & 15);

  f32x4 acc[8][4];
#pragma unroll
  for (int mi = 0; mi < 8; mi++)
#pragma unroll
    for (int ni = 0; ni < 4; ni++) acc[mi][ni] = (f32x4){0.f, 0.f, 0.f, 0.f};

#define LDA4(DST, RO, F0) \
  _Pragma("unroll") \
  for (int f = 0; f < 4; f++) \
    DST[f] = *reinterpret_cast<const bf16x8*>(&As[(RO) + (arow0 + ((F0) + f) * 16) * 32 + acoff]);
#define LDB4(DST, RO) \
  _Pragma("unroll") \
  for (int f = 0; f < 4; f++) \
    DST[f] = *reinterpret_cast<const bf16x8*>(&Bs[(RO) + (brow0 + f * 16) * 32 + acoff]);
#define BARF() \
  __builtin_amdgcn_s_barrier(); \
  asm volatile("" ::: "memory");
#define MMAQ(M0, AF, BF) \
  __builtin_amdgcn_s_setprio(1); \
  _Pragma("unroll") \
  for (int mi = 0; mi < 4; mi++) \
    _Pragma("unroll") \
    for (int ni = 0; ni < 4; ni++) \
      acc[(M0) + mi][ni] = __builtin_amdgcn_mfma_f32_16x16x32_bf16(AF[mi], BF[ni], acc[(M0) + mi][ni], 0, 0, 0); \
  __builtin_amdgcn_s_setprio(0);

  // prologue: tile0 (buf0) + tile1 kh0 (buf1) = 6 units; retire tile0's 4.
  stage_unit(gA, As, 0, 0, 0);
  stage_unit(gB, Bs, 0, 0, 0);
  stage_unit(gA, As, 0, 1, 0);
  stage_unit(gB, Bs, 0, 1, 0);
  stage_unit(gA, As, 1, 0, 1);
  stage_unit(gB, Bs, 1, 0, 1);
  asm volatile("s_waitcnt vmcnt(4)" ::: "memory");

  for (int it = 0; it < NTILES / 2; ++it) {
    const int t2 = it * 2;
    const bool pf = (t2 + 2 < NTILES);
    bf16x8 a0[4], a1[4], b0[4], c0[4], c1[4], d0[4];
    // ---- P1: MFMA buf0kh0 M0-3; load a0,b0,a1 (12) ----
    BARF()
    stage_unit(gA, As, t2 + 1, 1, 1);
    LDA4(a0, 0, 0) LDB4(b0, 0) LDA4(a1, 0, 4)
    MMAQ(0, a0, b0)
    // ---- P2: MFMA buf0kh0 M4-7; load c0,d0 <- buf0kh1 (8) ----
    BARF()
    stage_unit(gB, Bs, t2 + 1, 1, 1);
    LDA4(c0, 8192, 0) LDB4(d0, 8192)
    MMAQ(4, a1, b0)
    // ---- P3: MFMA buf0kh1 M0-3; load c1 (4) ----
    BARF()
    if (pf) stage_unit(gA, As, t2 + 2, 0, 0);
    LDA4(c1, 8192, 4)
    MMAQ(0, c0, d0)
    // ---- P4: MFMA buf0kh1 M4-7; counted vmcnt ----
    BARF()
    if (pf) stage_unit(gB, Bs, t2 + 2, 0, 0);
    MMAQ(4, c1, d0)
    if (pf) { asm volatile("s_waitcnt vmcnt(4)" ::: "memory"); }
    else    { asm volatile("s_waitcnt vmcnt(0)" ::: "memory"); }
    // ---- P5: MFMA buf1kh0 M0-3; load a0,b0,a1 (12) ----
    BARF()
    if (pf) stage_unit(gA, As, t2 + 2, 1, 0);
    LDA4(a0, 16384, 0) LDB4(b0, 16384) LDA4(a1, 16384, 4)
    MMAQ(0, a0, b0)
    // ---- P6: MFMA buf1kh0 M4-7; load c0,d0 <- buf1kh1 (8) ----
    BARF()
    if (pf) stage_unit(gB, Bs, t2 + 2, 1, 0);
    LDA4(c0, 24576, 0) LDB4(d0, 24576)
    MMAQ(4, a1, b0)
    // ---- P7: MFMA buf1kh1 M0-3; load c1 (4) ----
    BARF()
    if (pf) stage_unit(gA, As, t2 + 3, 0, 1);
    LDA4(c1, 24576, 4)
    MMAQ(0, c0, d0)
    // ---- P8: MFMA buf1kh1 M4-7; counted vmcnt ----
    BARF()
    if (pf) stage_unit(gB, Bs, t2 + 3, 0, 1);
    MMAQ(4, c1, d0)
    if (pf) { asm volatile("s_waitcnt vmcnt(4)" ::: "memory"); }
  }

  // ---- epilogue: tanh(.+bW)*v, reduce over N within block ----
  float sp[8][4];
#pragma unroll
  for (int mi = 0; mi < 8; mi++)
#pragma unroll
    for (int r = 0; r < 4; r++) sp[mi][r] = 0.f;

#pragma unroll
  for (int ni = 0; ni < 4; ni++) {
    const int col = nbase + wn * 64 + ni * 16 + (lane & 15);
    const float bwv = bW[col];
    const float vv  = v[col];
#pragma unroll
    for (int mi = 0; mi < 8; mi++)
#pragma unroll
      for (int r = 0; r < 4; r++) {
        float xv = acc[mi][ni][r] + bwv;
        xv = fminf(fmaxf(xv, -15.f), 15.f);
        const float e = __expf(2.f * xv);
        sp[mi][r] += vv * (e - 1.f) / (e + 1.f);   // tanh
      }
  }
#pragma unroll
  for (int mi = 0; mi < 8; mi++)
#pragma unroll
    for (int r = 0; r < 4; r++) {
      float sv = sp[mi][r];
      sv += __shfl_xor(sv, 1);
      sv += __shfl_xor(sv, 2);
      sv += __shfl_xor(sv, 4);
      sv += __shfl_xor(sv, 8);
      sp[mi][r] = sv;
    }
  if ((lane & 15) == 0) {
#pragma unroll
    for (int mi = 0; mi < 8; mi++)
#pragma unroll
      for (int r = 0; r < 4; r++)
        s_red[wn][wm * 128 + mi * 16 + (lane >> 4) * 4 + r] = sp[mi][r];
  }
  __syncthreads();
  if (tid < 256)
    spart[(size_t)nt * BT + mbase + tid] =
        s_red[0][tid] + s_red[1][tid] + s_red[2][tid] + s_red[3][tid];
}

// ---------------- Kernel 4: softmax over T per batch ----------------
__global__ __launch_bounds__(512) void softmax_kernel(
    const float* __restrict__ spart, const float* __restrict__ bv,
    float* __restrict__ wout) {
  const int b = blockIdx.x, t = threadIdx.x;
  float s = bv[0];
#pragma unroll
  for (int p = 0; p < NSPLIT; p++) s += spart[(size_t)p * BT + b * TT + t];
  if (s != s) s = 0.f;                       // nan_to_num
  s = fminf(fmaxf(s, -10.f), 10.f);          // clip
  float m = s;
#pragma unroll
  for (int off = 32; off >= 1; off >>= 1) m = fmaxf(m, __shfl_xor(m, off));
  __shared__ float redm[8], reds[8];
  const int w = t >> 6;
  if ((t & 63) == 0) redm[w] = m;
  __syncthreads();
  m = redm[0];
#pragma unroll
  for (int i = 1; i < 8; i++) m = fmaxf(m, redm[i]);
  const float e = expf(s - m);
  float su = e;
#pragma unroll
  for (int off = 32; off >= 1; off >>= 1) su += __shfl_xor(su, off);
  if ((t & 63) == 0) reds[w] = su;
  __syncthreads();
  su = 0.f;
#pragma unroll
  for (int i = 0; i < 8; i++) su += reds[i];
  wout[b * TT + t] = e / su;
}

// ---------------- Kernel 5: context partials over t-chunks ----------------
__global__ __launch_bounds__(256) void ctx_part_kernel(
    const unsigned short* __restrict__ xb, const float* __restrict__ wts,
    float* __restrict__ ctxp) {
  const int b = blockIdx.x, c = blockIdx.y, tid = threadIdx.x;
  const int h = tid * 4;
  float a0 = 0.f, a1 = 0.f, a2 = 0.f, a3 = 0.f;
  const unsigned short* xrow = xb + ((size_t)(b * TT + c * 64)) * H + h;
  const float* wrow = wts + b * TT + c * 64;
  for (int t = 0; t < 64; t++) {
    const float wgt = wrow[t];
    const ushort4 xv = *reinterpret_cast<const ushort4*>(xrow + (size_t)t * H);
    a0 += wgt * bf2f(xv.x);
    a1 += wgt * bf2f(xv.y);
    a2 += wgt * bf2f(xv.z);
    a3 += wgt * bf2f(xv.w);
  }
  float4 o = {a0, a1, a2, a3};
  *reinterpret_cast<float4*>(ctxp + ((size_t)c * BSZ + b) * H + h) = o;
}

// ---------------- Kernel 6: context reduce ----------------
__global__ __launch_bounds__(256) void ctx_reduce_kernel(
    const float* __restrict__ ctxp, float* __restrict__ out) {
  const int idx = blockIdx.x * 256 + threadIdx.x;  // 0..65535 = b*H+h
  float s = 0.f;
#pragma unroll
  for (int c = 0; c < 8; c++) s += ctxp[(size_t)c * (BSZ * H) + idx];
  out[idx] = s;
}

extern "C" void kernel_launch(void* const* d_in, const int* in_sizes, int n_in,
                              void* d_out, int out_size, void* d_ws, size_t ws_size,
                              hipStream_t stream) {
  const float* lstm  = (const float*)d_in[0];
  const float* W     = (const float*)d_in[1];
  const float* bW    = (const float*)d_in[2];
  const float* v     = (const float*)d_in[3];
  const float* bv    = (const float*)d_in[4];
  const float* gamma = (const float*)d_in[5];
  const float* beta  = (const float*)d_in[6];
  float* out = (float*)d_out;

  char* ws = (char*)d_ws;
  unsigned short* xb = (unsigned short*)ws;                                   // 64 MiB
  unsigned short* wb = (unsigned short*)(ws + (size_t)BT * H * 2);            // 2 MiB
  float* spart = (float*)(ws + (size_t)BT * H * 2 + (size_t)H * H * 2);       // 512 KiB
  float* ctxp  = (float*)((char*)spart + (size_t)NSPLIT * BT * 4);            // 2 MiB

  float* weights_out = out + BSZ * H;   // context first (65536), then weights (32768)

  ln_kernel<<<BT, 256, 0, stream>>>(lstm, gamma, beta, xb);
  wcvt_kernel<<<(H * H) / 1024, 256, 0, stream>>>(W, wb);
  score_gemm<<<512, 512, 0, stream>>>(xb, wb, bW, v, spart);
  softmax_kernel<<<BSZ, TT, 0, stream>>>(spart, bv, weights_out);
  ctx_part_kernel<<<dim3(BSZ, 8), 256, 0, stream>>>(xb, weights_out, ctxp);
  ctx_reduce_kernel<<<(BSZ * H) / 256, 256, 0, stream>>>(ctxp, out);
}